// Round 2
// baseline (657.175 us; speedup 1.0000x reference)
//
#include <hip/hip_runtime.h>

#define NB 256       // batch
#define NT_ 2048     // timesteps
#define DIN 64
#define DH 128
#define HB 64        // h-channels per block (h-split: 2 blocks per batch)
#define TT 32        // time tile
#define NTILES (NT_ / TT)   // 64

// LDS: xs 2*32*64*4 = 16 KB, ffs 2*32*64*4 = 16 KB -> 32 KB/block.
// W is pinned in VGPRs via inline-asm loads (not remat-able by the compiler):
// 16 x global_load_dwordx4 = 64 VGPRs, under the 102-VGPR cap of
// __launch_bounds__(576, 5). 2 blocks/CU = 18 waves.

typedef const __attribute__((address_space(1))) void gptr_t;
typedef __attribute__((address_space(3))) void lptr_t;
typedef __attribute__((ext_vector_type(4))) float f32x4;

__device__ __forceinline__ void scan_tile(const float* ffs_buf, float& mem, float& spk,
                                          float* op, int t0, int lane) {
    #pragma unroll
    for (int tt = 0; tt < TT; ++tt) {
        float f = ffs_buf[tt * HB + lane];
        mem = fmaf(0.9f, mem, f - spk);
        // sigmoid(5*(mem-1)) = 1/(1+2^(-5*log2e*(mem-1)))
        float e = __builtin_amdgcn_exp2f(-7.213475204444817f * (mem - 1.f));
        spk = __builtin_amdgcn_rcpf(1.f + e);
        op[(size_t)(t0 + tt) * DH] = spk;
    }
}

// one k-slice of 4: x float4 (LDS broadcast) * W float4 (pinned VGPRs)
#define KSTEP(WREG, KK) { \
    float4 xv = xt[KK]; \
    a0 = fmaf(xv.x, WREG[0], a0); \
    a1 = fmaf(xv.y, WREG[1], a1); \
    a2 = fmaf(xv.z, WREG[2], a2); \
    a3 = fmaf(xv.w, WREG[3], a3); }

__global__ __launch_bounds__(576, 5) void snn_fused_kernel(
    const float* __restrict__ x, const float* __restrict__ W,
    const float* __restrict__ bias, float* __restrict__ out)
{
    __shared__ float xs[2][TT * DIN];   // staged x tiles
    __shared__ float ffs[2][TT * HB];   // produced ff tiles

    const int tid   = threadIdx.x;
    const int wv    = tid >> 6;         // 0..8 (waves 0-7: GEMM, wave 8: scan)
    const int lane  = tid & 63;
    const int b     = blockIdx.x >> 1;
    const int hhalf = blockIdx.x & 1;

    const float* xb = x + (size_t)b * NT_ * DIN;

    if (wv < 8) {
        // ---------------- producer: GEMM waves ----------------
        // each thread: one h (= hhalf*64 + lane), 4 wave-uniform timesteps/tile
        const int h = hhalf * HB + lane;
        const float bh = bias[h];

        // W row pinned in VGPRs: asm loads cannot be rematerialized, so the
        // allocator must keep all 64 registers live across the tile loop.
        f32x4 w0, w1, w2, w3, w4_, w5, w6, w7, w8, w9, w10, w11, w12, w13, w14, w15;
        {
            const float* Wrow = W + (size_t)h * DIN;
            asm volatile(
                "global_load_dwordx4 %0,  %16, off\n\t"
                "global_load_dwordx4 %1,  %16, off offset:16\n\t"
                "global_load_dwordx4 %2,  %16, off offset:32\n\t"
                "global_load_dwordx4 %3,  %16, off offset:48\n\t"
                "global_load_dwordx4 %4,  %16, off offset:64\n\t"
                "global_load_dwordx4 %5,  %16, off offset:80\n\t"
                "global_load_dwordx4 %6,  %16, off offset:96\n\t"
                "global_load_dwordx4 %7,  %16, off offset:112\n\t"
                "global_load_dwordx4 %8,  %16, off offset:128\n\t"
                "global_load_dwordx4 %9,  %16, off offset:144\n\t"
                "global_load_dwordx4 %10, %16, off offset:160\n\t"
                "global_load_dwordx4 %11, %16, off offset:176\n\t"
                "global_load_dwordx4 %12, %16, off offset:192\n\t"
                "global_load_dwordx4 %13, %16, off offset:208\n\t"
                "global_load_dwordx4 %14, %16, off offset:224\n\t"
                "global_load_dwordx4 %15, %16, off offset:240\n\t"
                "s_waitcnt vmcnt(0)"
                : "=&v"(w0), "=&v"(w1), "=&v"(w2),  "=&v"(w3),
                  "=&v"(w4_), "=&v"(w5), "=&v"(w6),  "=&v"(w7),
                  "=&v"(w8), "=&v"(w9), "=&v"(w10), "=&v"(w11),
                  "=&v"(w12), "=&v"(w13), "=&v"(w14), "=&v"(w15)
                : "v"(Wrow));
        }

        const int loff = tid * 4;   // float offset into x tile (512 thr * 16B = 8KB)

        // preload x tile 0 (async global->LDS, wave-uniform base + lane*16B)
        __builtin_amdgcn_global_load_lds((gptr_t*)(xb + loff),
                                         (lptr_t*)(&xs[0][loff]), 16, 0, 0);
        __syncthreads();   // [barrier 0]

        for (int it = 0; it < NTILES; ++it) {
            const int buf = it & 1;
            // async prefetch next x tile into other buffer (drained by end barrier)
            if (it + 1 < NTILES) {
                __builtin_amdgcn_global_load_lds(
                    (gptr_t*)(xb + (size_t)(it + 1) * TT * DIN + loff),
                    (lptr_t*)(&xs[buf ^ 1][loff]), 16, 0, 0);
            }
            // compute ff for 4 wave-uniform timesteps (broadcast LDS reads)
            #pragma unroll
            for (int i = 0; i < 4; ++i) {
                const int t = wv * 4 + i;
                const float4* xt = (const float4*)&xs[buf][t * DIN];
                float a0 = 0.f, a1 = 0.f, a2 = 0.f, a3 = 0.f;
                KSTEP(w0, 0)  KSTEP(w1, 1)  KSTEP(w2, 2)   KSTEP(w3, 3)
                KSTEP(w4_, 4) KSTEP(w5, 5)  KSTEP(w6, 6)   KSTEP(w7, 7)
                KSTEP(w8, 8)  KSTEP(w9, 9)  KSTEP(w10, 10) KSTEP(w11, 11)
                KSTEP(w12, 12) KSTEP(w13, 13) KSTEP(w14, 14) KSTEP(w15, 15)
                ffs[buf][t * HB + lane] = (a0 + a1) + (a2 + a3) + bh;
            }
            __syncthreads();   // [barrier 1+it] ff tile it published
        }
    } else {
        // ---------------- consumer: scan wave ----------------
        float mem = 0.f, spk = 0.f;
        float* op = out + (size_t)b * NT_ * DH + hhalf * HB + lane;

        __syncthreads();   // [barrier 0]
        for (int it = 0; it < NTILES; ++it) {
            if (it > 0) {
                scan_tile(ffs[(it - 1) & 1], mem, spk, op, (it - 1) * TT, lane);
            }
            __syncthreads();   // [barrier 1+it]
        }
        // drain: last tile (GEMM waves have exited; no barrier needed)
        scan_tile(ffs[(NTILES - 1) & 1], mem, spk, op, (NTILES - 1) * TT, lane);
    }
}

extern "C" void kernel_launch(void* const* d_in, const int* in_sizes, int n_in,
                              void* d_out, int out_size, void* d_ws, size_t ws_size,
                              hipStream_t stream) {
    const float* x  = (const float*)d_in[0];
    const float* W  = (const float*)d_in[1];
    const float* bb = (const float*)d_in[2];
    float* out = (float*)d_out;
    snn_fused_kernel<<<dim3(NB * 2), dim3(576), 0, stream>>>(x, W, bb, out);
}

// Round 3
// 380.479 us; speedup vs baseline: 1.7272x; 1.7272x over previous
//
#include <hip/hip_runtime.h>

#define NB 256       // batch
#define NT_ 2048     // timesteps
#define DIN 64
#define DH 128
#define HB 64        // h-channels per block (h-split: 2 blocks per batch)
#define TT 32        // time tile
#define NTILES (NT_ / TT)   // 64

// Structure: 4 MFMA waves (each owns one 16-h tile) + 1 scan wave.
// GEMM via v_mfma_f32_16x16x32_bf16 with fp32 -> bf16 hi/lo split:
//   x*W ~= x_hi*W_hi + x_lo*W_hi + x_hi*W_lo   (error ~1e-4 << 0.0039 tol)
// x tile staged global->LDS with XOR-swizzled SOURCE address so the
// A-fragment ds_read_b128 (row stride 256B) is bank-conflict-free.
// LDS: xs 2*8KB + ffs 2*8KB = 32 KB/block; grid 512 -> 2 blocks/CU.

typedef const __attribute__((address_space(1))) void gptr_t;
typedef __attribute__((address_space(3))) void lptr_t;
typedef __attribute__((ext_vector_type(4))) float f32x4;
typedef __attribute__((ext_vector_type(8))) short bf16x8;
typedef __attribute__((ext_vector_type(4))) unsigned int u32x4;

// top-16-bit (bf16 truncation) of f, kept as fp32
__device__ __forceinline__ float hif(float f) {
    return __uint_as_float(__float_as_uint(f) & 0xFFFF0000u);
}
// pack hi16(ev), hi16(od) -> one u32 (ev in low half): v_perm_b32
__device__ __forceinline__ unsigned int pkhi(float ev, float od) {
    return __builtin_amdgcn_perm(__float_as_uint(od), __float_as_uint(ev), 0x07060302u);
}
// 8 floats -> 8 bf16 (truncation)
__device__ __forceinline__ bf16x8 pack_hi8(float4 a, float4 b) {
    union { u32x4 u; bf16x8 v; } t;
    t.u.x = pkhi(a.x, a.y); t.u.y = pkhi(a.z, a.w);
    t.u.z = pkhi(b.x, b.y); t.u.w = pkhi(b.z, b.w);
    return t.v;
}
__device__ __forceinline__ float4 resid4(float4 f) {
    float4 r;
    r.x = f.x - hif(f.x); r.y = f.y - hif(f.y);
    r.z = f.z - hif(f.z); r.w = f.w - hif(f.w);
    return r;
}

__device__ __forceinline__ void scan_tile(const float* ffs_buf, float& mem, float& spk,
                                          float* op, int t0, int lane) {
    #pragma unroll
    for (int tt = 0; tt < TT; ++tt) {
        // read with the C-write XOR swizzle: col = h ^ (((t>>2)&3)<<4)
        float f = ffs_buf[tt * HB + (lane ^ (((tt >> 2) & 3) << 4))];
        mem = fmaf(0.9f, mem, f - spk);
        // sigmoid(5*(mem-1)) = 1/(1+2^(-5*log2e*(mem-1)))
        float e = __builtin_amdgcn_exp2f(-7.213475204444817f * (mem - 1.f));
        spk = __builtin_amdgcn_rcpf(1.f + e);
        op[(size_t)(t0 + tt) * DH] = spk;
    }
}

// stage one 32x64 fp32 x tile (8KB) with 256 threads (waves 0-3), 2 issues each.
// LDS dest is linear; global SOURCE is inverse-swizzled so that LDS[row][c]
// holds x[row][c ^ ((row&7)<<5 bytes)] -> conflict-free A-frag reads.
#define STAGE(DB, IT) { \
    _Pragma("unroll") \
    for (int j = 0; j < 2; ++j) { \
        const int idx = j * 256 + tid; \
        const int row = idx >> 4; \
        const int swf = ((((idx & 15) << 4) ^ ((row & 7) << 5)) >> 2); \
        __builtin_amdgcn_global_load_lds( \
            (gptr_t*)(xb + (size_t)(IT) * TT * DIN + row * DIN + swf), \
            (lptr_t*)(&xs[DB][idx * 4]), 16, 0, 0); \
    } }

__global__ __launch_bounds__(320, 3) void snn_fused_kernel(
    const float* __restrict__ x, const float* __restrict__ W,
    const float* __restrict__ bias, float* __restrict__ out)
{
    __shared__ float xs[2][TT * DIN];   // staged x tiles (source-swizzled)
    __shared__ float ffs[2][TT * HB];   // ff tiles (C-layout swizzled)

    const int tid   = threadIdx.x;
    const int wv    = tid >> 6;         // 0..4 (0-3: MFMA, 4: scan)
    const int lane  = tid & 63;
    const int b     = blockIdx.x >> 1;
    const int hhalf = blockIdx.x & 1;

    const float* xb = x + (size_t)b * NT_ * DIN;

    if (wv < 4) {
        // ---------------- producer: MFMA waves ----------------
        const int l15 = lane & 15;
        const int lg  = lane >> 4;           // 0..3
        const int hrow = hhalf * HB + wv * 16 + l15;
        const float bh = bias[hrow];

        // B fragments (W^T slices), hi+lo, resident in VGPRs (16 regs total).
        // B[k][h]: lane holds k = kh*32 + lg*8 + j, h = wv*16 + l15
        // = 8 consecutive floats of W row hrow.
        bf16x8 bhi[2], blo[2];
        #pragma unroll
        for (int kh = 0; kh < 2; ++kh) {
            const float* wp = W + (size_t)hrow * DIN + kh * 32 + lg * 8;
            float4 g0 = *(const float4*)wp;
            float4 g1 = *(const float4*)(wp + 4);
            bhi[kh] = pack_hi8(g0, g1);
            blo[kh] = pack_hi8(resid4(g0), resid4(g1));
        }

        STAGE(0, 0)                          // preload x tile 0
        __syncthreads();                     // [barrier 0]

        const int asw = (lane & 7) << 5;     // A-read swizzle key (row&7 == lane&7)
        const int cw  = (wv * 16 + l15) ^ (lg << 4);   // swizzled ffs column

        for (int it = 0; it < NTILES; ++it) {
            const int buf = it & 1;
            if (it + 1 < NTILES) STAGE(buf ^ 1, it + 1)   // async prefetch

            f32x4 acc0 = {bh, bh, bh, bh};   // C-tile t=0..15 (bias pre-added)
            f32x4 acc1 = {bh, bh, bh, bh};   // C-tile t=16..31
            #pragma unroll
            for (int kh = 0; kh < 2; ++kh) {
                // A frags: lane reads x[t][kh*32 + lg*8 .. +7], t = ct*16+l15
                const int koff = (kh * 128 + (lg << 5)) ^ asw;
                const char* base = (const char*)xs[buf];
                const float4* p0 = (const float4*)(base + l15 * 256 + koff);
                const float4* p1 = (const float4*)(base + (16 + l15) * 256 + koff);
                float4 f0 = p0[0], f1 = p0[1];
                float4 g0 = p1[0], g1 = p1[1];
                bf16x8 a0h = pack_hi8(f0, f1);
                bf16x8 a1h = pack_hi8(g0, g1);
                bf16x8 a0l = pack_hi8(resid4(f0), resid4(f1));
                bf16x8 a1l = pack_hi8(resid4(g0), resid4(g1));
                acc0 = __builtin_amdgcn_mfma_f32_16x16x32_bf16(a0h, bhi[kh], acc0, 0, 0, 0);
                acc1 = __builtin_amdgcn_mfma_f32_16x16x32_bf16(a1h, bhi[kh], acc1, 0, 0, 0);
                acc0 = __builtin_amdgcn_mfma_f32_16x16x32_bf16(a0l, bhi[kh], acc0, 0, 0, 0);
                acc1 = __builtin_amdgcn_mfma_f32_16x16x32_bf16(a1l, bhi[kh], acc1, 0, 0, 0);
                acc0 = __builtin_amdgcn_mfma_f32_16x16x32_bf16(a0h, blo[kh], acc0, 0, 0, 0);
                acc1 = __builtin_amdgcn_mfma_f32_16x16x32_bf16(a1h, blo[kh], acc1, 0, 0, 0);
            }
            // C write: lane holds C[row=lg*4+r][col=l15]; swizzle col by lg
            #pragma unroll
            for (int r = 0; r < 4; ++r) {
                ffs[buf][(lg * 4 + r) * HB + cw]        = acc0[r];
                ffs[buf][(16 + lg * 4 + r) * HB + cw]   = acc1[r];
            }
            __syncthreads();                 // [barrier 1+it] ff tile published
        }
    } else {
        // ---------------- consumer: scan wave ----------------
        float mem = 0.f, spk = 0.f;
        float* op = out + (size_t)b * NT_ * DH + hhalf * HB + lane;

        __syncthreads();                     // [barrier 0]
        for (int it = 0; it < NTILES; ++it) {
            if (it > 0) {
                scan_tile(ffs[(it - 1) & 1], mem, spk, op, (it - 1) * TT, lane);
            }
            __syncthreads();                 // [barrier 1+it]
        }
        // drain: last tile (MFMA waves have exited; no barrier needed)
        scan_tile(ffs[(NTILES - 1) & 1], mem, spk, op, (NTILES - 1) * TT, lane);
    }
}

extern "C" void kernel_launch(void* const* d_in, const int* in_sizes, int n_in,
                              void* d_out, int out_size, void* d_ws, size_t ws_size,
                              hipStream_t stream) {
    const float* x  = (const float*)d_in[0];
    const float* W  = (const float*)d_in[1];
    const float* bb = (const float*)d_in[2];
    float* out = (float*)d_out;
    snn_fused_kernel<<<dim3(NB * 2), dim3(320), 0, stream>>>(x, W, bb, out);
}